// Round 16
// baseline (119.211 us; speedup 1.0000x reference)
//
#include <hip/hip_runtime.h>
#include <hip/hip_bf16.h>

#define NB   16384
#define NG   8
#define ND   2048
#define NR   6
#define NKC  48
#define NOUT 54
#define NT16 (NB / 16 + NG)       // 1032 tiles of 16 samples
#define AOFF 131072               // A region: 16 rows x 8KB fp32
#define LDSZ (AOFF + 4 * 3 * 2048)// + per-wave ring-3 B (24KB) = 155648
#define LROW 136                  // tier-3 fallback gemm
#define BM   32
#define KC   128
#define NCH  (ND / KC)
#define MAXT (NB / BM + NG)

typedef __attribute__((ext_vector_type(8))) short short8_t;
typedef __attribute__((ext_vector_type(4))) float f32x4;

__device__ __forceinline__ unsigned short f2bf(float x) {
    union { float f; unsigned u; } v; v.f = x;
    unsigned r = v.u + 0x7FFFu + ((v.u >> 16) & 1u);   // RNE
    return (unsigned short)(r >> 16);
}

__device__ __forceinline__ short8_t cvt8(float4 a, float4 b) {
    short8_t s;
    s[0] = (short)f2bf(a.x); s[1] = (short)f2bf(a.y);
    s[2] = (short)f2bf(a.z); s[3] = (short)f2bf(a.w);
    s[4] = (short)f2bf(b.x); s[5] = (short)f2bf(b.y);
    s[6] = (short)f2bf(b.z); s[7] = (short)f2bf(b.w);
    return s;
}

__device__ __forceinline__ void gl_lds16(const void* g, void* s) {
    __builtin_amdgcn_global_load_lds(
        (const __attribute__((address_space(1))) void*)g,
        (__attribute__((address_space(3))) void*)s,
        16, 0, 0);
}

#define WAITV(N) do { asm volatile("s_waitcnt vmcnt(" #N ")" ::: "memory"); \
                      __builtin_amdgcn_sched_barrier(0); } while (0)
#define BAR() do { __builtin_amdgcn_s_barrier(); \
                   __builtin_amdgcn_sched_barrier(0); } while (0)

// ---- histogram (tier-3) ----
__global__ void hist_kernel(const int* __restrict__ roi, int* __restrict__ counts) {
    int i = blockIdx.x * 256 + threadIdx.x;
    int g = roi[i];
    int lane = threadIdx.x & 63;
    #pragma unroll
    for (int gg = 0; gg < NG; ++gg) {
        unsigned long long m = __ballot(g == gg);
        if (m && lane == (int)(__ffsll((unsigned long long)m) - 1))
            atomicAdd(&counts[gg], (int)__popcll(m));
    }
}

// ---- scatter into packed regions (tier-3) ----
__global__ void scatter_kernel(const int* __restrict__ roi, const int* __restrict__ counts,
                               int* __restrict__ ranks, int* __restrict__ perm) {
    int off[NG];
    int acc = 0;
    #pragma unroll
    for (int gg = 0; gg < NG; ++gg) { off[gg] = acc; acc += counts[gg]; }
    int i = blockIdx.x * 256 + threadIdx.x;
    int g = roi[i];
    int lane = threadIdx.x & 63;
    #pragma unroll
    for (int gg = 0; gg < NG; ++gg) {
        unsigned long long m = __ballot(g == gg);
        if (!m) continue;
        int leader = (int)(__ffsll((unsigned long long)m) - 1);
        int base = 0;
        if (lane == leader) base = atomicAdd(&ranks[gg], (int)__popcll(m));
        base = __shfl(base, leader);
        if (g == gg) {
            int rank = (int)__popcll(m & ((1ull << lane) - 1ull));
            perm[off[gg] + base + rank] = i;
        }
    }
}

// ---- merged pre-pass: blocks 0..63 scatter roi; 64..575 build the W blob ----
// blob unit u (16B): l=u&63, ks=(u>>6)&1, c=(u>>7)&31, w=(u>>12)&3, g=u>>14
// content = W[g][w*16 + (l&15)][c*64 + ks*32 + (l>>4)*8 .. +8)
__global__ void prep_kernel(const int* __restrict__ roi, int* __restrict__ cnt,
                            int* __restrict__ perm,
                            const float* __restrict__ Wreg, const float* __restrict__ Wcls,
                            short* __restrict__ Wbf) {
    if (blockIdx.x < 64) {
        int i = blockIdx.x * 256 + threadIdx.x;
        int g = roi[i];
        int lane = threadIdx.x & 63;
        #pragma unroll
        for (int gg = 0; gg < NG; ++gg) {
            unsigned long long m = __ballot(g == gg);
            if (!m) continue;
            int leader = (int)(__ffsll((unsigned long long)m) - 1);
            int base = 0;
            if (lane == leader) base = atomicAdd(&cnt[gg], (int)__popcll(m));
            base = __shfl(base, leader);
            if (g == gg) {
                int rank = (int)__popcll(m & ((1ull << lane) - 1ull));
                perm[gg * NB + base + rank] = i;
            }
        }
    } else {
        int u = (blockIdx.x - 64) * 256 + threadIdx.x;   // 131072 units
        int l  = u & 63;
        int ks = (u >> 6) & 1;
        int c  = (u >> 7) & 31;
        int w  = (u >> 12) & 3;
        int g  = u >> 14;
        int row = w * 16 + (l & 15);
        int k   = c * 64 + ks * 32 + (l >> 4) * 8;
        short8_t v = {0, 0, 0, 0, 0, 0, 0, 0};
        if (row < NOUT) {
            const float* s = (row < NR) ? Wreg + (size_t)(g * NR + row) * ND + k
                                        : Wcls + (size_t)(g * NKC + row - NR) * ND + k;
            float4 a = *(const float4*)s;
            float4 b = *(const float4*)(s + 4);
            v = cvt8(a, b);
        }
        *(short8_t*)(Wbf + (size_t)u * 8) = v;
    }
}

// ---- primary: K-resident GEMM — each feats row read as ONE 8KB sequential burst ----
// 1032 blocks x 4 waves. Tile = 16 samples; A = 16 x 8KB fp32 resident in LDS
// (wave w stages rows 4w..4w+3, 8 consecutive 1KB gl_lds per row, 16B-XOR
// involution within each 1KB window). ONE barrier per tile; compute loop is
// barrier-free: wave w owns cols 16w..16w+15, B wave-private ring-3 (2KB/chunk
// from the L2-resident blob), 2-AHEAD prefetch (write slot (c+2)%3 != read
// slot c%3 — fixes R15's WAR race), counted WAITV(4). 32 chunks of KC=64.
__launch_bounds__(256, 1)
__global__ void gemm_res_kernel(const float* __restrict__ feats,
                                const short* __restrict__ Wbf,
                                const float* __restrict__ breg, const float* __restrict__ bcls,
                                const int* __restrict__ cnt, const int* __restrict__ perm,
                                float* __restrict__ out) {
    __shared__ __align__(16) char lds[LDSZ];
    __shared__ int sRow[16];

    int tid = threadIdx.x, w = tid >> 6, l = tid & 63, lr = l & 15, lq = l >> 4;

    int ts[NG + 1]; ts[0] = 0;
    #pragma unroll
    for (int gg = 0; gg < NG; ++gg) ts[gg + 1] = ts[gg] + ((cnt[gg] + 15) >> 4);
    int b = blockIdx.x;
    if (b >= ts[NG]) return;
    int g = 0;
    #pragma unroll
    for (int gg = 0; gg < NG; ++gg) if (b >= ts[gg + 1]) g = gg + 1;
    int cg = cnt[g];
    if (cg <= 0) return;
    int rbase = (b - ts[g]) * 16;
    int nv = cg - rbase; if (nv > 16) nv = 16;

    if (tid < 16) {
        int r = rbase + tid;
        if (r >= cg) r = cg - 1;      // clamp; stores masked by nv
        sRow[tid] = perm[g * NB + r];
    }
    __syncthreads();

    const char* f = (const char*)feats;
    const char* bSrc = (const char*)Wbf + (size_t)(g * 4 + w) * 32 * 2048 + l * 16;
    char* Bb = lds + AOFF + w * 6144;            // wave-private ring-3 (3 x 2KB)

    // ---- A burst: wave w stages rows 4w..4w+3 as 8 consecutive 1KB loads each.
    // XOR involution: LDS unit s of row r holds global unit s^(r&7).
    #pragma unroll
    for (int rr = 0; rr < 4; ++rr) {
        const int r = 4 * w + rr;
        const char* src = f + (size_t)sRow[r] * 8192 + ((l ^ (r & 7)) << 4);
        char* dst = lds + r * 8192;
        #pragma unroll
        for (int kk = 0; kk < 8; ++kk)
            gl_lds16(src + kk * 1024, dst + kk * 1024);
    }
    // ---- B prologue: chunks 0,1 into slots 0,1 (2-ahead steady state) ----
    gl_lds16(bSrc,        Bb);
    gl_lds16(bSrc + 1024, Bb + 1024);
    gl_lds16(bSrc + 2048, Bb + 2048);
    gl_lds16(bSrc + 3072, Bb + 3072);
    WAITV(2);    // all 32 A + B(0) landed; B(1) in flight
    BAR();       // every wave's A visible

    // ---- barrier-free compute loop ----
    f32x4 acc = {0, 0, 0, 0};
    const int key = lr & 7;
    const char* Arow = lds + lr * 8192;

    #pragma unroll
    for (int c = 0; c < 32; ++c) {
        const int sl = c % 3;
        if (c + 2 < 32) {
            const char* bs = bSrc + (size_t)(c + 2) * 2048;
            char* bd = Bb + ((c + 2) % 3) * 2048;    // != read slot c%3 (WAR-safe)
            gl_lds16(bs, bd);
            gl_lds16(bs + 1024, bd + 1024);
            WAITV(4);                  // B(c) landed; B(c+1),B(c+2) in flight
        } else if (c == 30) { WAITV(2); }
        else                { WAITV(0); }
        #pragma unroll
        for (int ks = 0; ks < 2; ++ks) {
            const int U0 = c * 16 + ks * 8 + lq * 2;
            float4 a0 = *(const float4*)(Arow + ((U0 ^ key) << 4));
            float4 a1 = *(const float4*)(Arow + (((U0 + 1) ^ key) << 4));
            short8_t af = cvt8(a0, a1);
            short8_t bf = *(const short8_t*)(Bb + sl * 2048 + ks * 1024 + l * 16);
            acc = __builtin_amdgcn_mfma_f32_16x16x32_bf16(af, bf, acc, 0, 0, 0);
        }
    }

    // ---- epilogue: bias + scatter to routed rows (wave w -> cols 16w..16w+15) ----
    const int B6 = NB * NR;
    int col = w * 16 + lr;
    if (col < NOUT) {
        float bias = (col < NR) ? breg[g * NR + col] : bcls[g * NKC + (col - NR)];
        #pragma unroll
        for (int j = 0; j < 4; ++j) {
            int row = lq * 4 + j;
            if (row < nv) {
                int smp = sRow[row];
                if (col < NR) out[smp * NR + col] = acc[j] + bias;
                else          out[B6 + smp * NKC + (col - NR)] = acc[j] + bias;
            }
        }
    }
}

// ---- tier-3 GEMM (proven R3 path, no blob needed) ----
__launch_bounds__(256, 3)
__global__ void gemm_kernel(const float* __restrict__ feats,
                            const float* __restrict__ Wreg, const float* __restrict__ breg,
                            const float* __restrict__ Wcls, const float* __restrict__ bcls,
                            const int* __restrict__ counts, const int* __restrict__ perm,
                            float* __restrict__ out, int stride) {
    __shared__ __align__(16) short Bsh[2][64][LROW];
    __shared__ int sRow[BM];

    int ts[NG + 1]; ts[0] = 0;
    int off[NG]; int acc = 0;
    #pragma unroll
    for (int gg = 0; gg < NG; ++gg) {
        int c = counts[gg];
        off[gg] = stride ? gg * stride : acc;
        acc += c;
        ts[gg + 1] = ts[gg] + (c + BM - 1) / BM;
    }
    int b = blockIdx.x;
    if (b >= ts[NG]) return;
    int g = 0;
    #pragma unroll
    for (int gg = 0; gg < NG; ++gg) if (b >= ts[gg + 1]) g = gg + 1;
    int gcnt  = counts[g];
    int goff  = off[g];
    int rbase = (b - ts[g]) * BM;
    int nvalid = gcnt - rbase; if (nvalid > BM) nvalid = BM;

    int tid = threadIdx.x;
    if (tid < BM) {
        int r = rbase + tid;
        if (r >= gcnt) r = gcnt - 1;
        sRow[tid] = perm[goff + r];
    }
    __syncthreads();

    int rB = tid >> 2;
    int cq = tid & 3;
    const float* wsrc = nullptr;
    if (rB < NR)        wsrc = Wreg + ((size_t)g * NR + rB) * ND + cq * 32;
    else if (rB < NOUT) wsrc = Wcls + ((size_t)g * NKC + (rB - NR)) * ND + cq * 32;

    int w = tid >> 6, l = tid & 63, lr = l & 15, lq = l >> 4;
    int mt = w & 1, nh = w >> 1;
    const float* aptr = feats + (size_t)sRow[mt * 16 + lr] * ND + lq * 8;
    const short* brp = (const short*)&Bsh[0][0][0] + (nh * 32 + lr) * LROW + lq * 8;

    f32x4 acc0 = {0, 0, 0, 0}, acc1 = {0, 0, 0, 0};
    float4 rb[8];

    if (wsrc) {
        #pragma unroll
        for (int i = 0; i < 8; ++i) rb[i] = *(const float4*)(wsrc + 4 * i);
    } else {
        #pragma unroll
        for (int i = 0; i < 8; ++i) rb[i] = make_float4(0.f, 0.f, 0.f, 0.f);
    }
    {
        short* bw = &Bsh[0][rB][cq * 32];
        #pragma unroll
        for (int j = 0; j < 4; ++j) *(short8_t*)(bw + 8 * j) = cvt8(rb[2 * j], rb[2 * j + 1]);
    }
    __syncthreads();

    #pragma unroll
    for (int c = 0; c < NCH; ++c) {
        const int cur = c & 1, nxt = cur ^ 1;
        if (c + 1 < NCH && wsrc) {
            const float* s = wsrc + (c + 1) * KC;
            #pragma unroll
            for (int i = 0; i < 8; ++i) rb[i] = *(const float4*)(s + 4 * i);
        }
        const short* bp = brp + cur * (64 * LROW);
        const float* ap = aptr + c * KC;
        #pragma unroll
        for (int ks = 0; ks < 4; ++ks) {
            float4 a0 = *(const float4*)(ap + ks * 32);
            float4 a1 = *(const float4*)(ap + ks * 32 + 4);
            short8_t af = cvt8(a0, a1);
            short8_t b0 = *(const short8_t*)(bp + ks * 32);
            short8_t b1 = *(const short8_t*)(bp + 16 * LROW + ks * 32);
            acc0 = __builtin_amdgcn_mfma_f32_16x16x32_bf16(af, b0, acc0, 0, 0, 0);
            acc1 = __builtin_amdgcn_mfma_f32_16x16x32_bf16(af, b1, acc1, 0, 0, 0);
        }
        if (c + 1 < NCH && wsrc) {
            short* bw = &Bsh[nxt][rB][cq * 32];
            #pragma unroll
            for (int j = 0; j < 4; ++j) *(short8_t*)(bw + 8 * j) = cvt8(rb[2 * j], rb[2 * j + 1]);
        } else if (c + 1 < NCH) {
            short8_t z = {0,0,0,0,0,0,0,0};
            short* bw = &Bsh[nxt][rB][cq * 32];
            #pragma unroll
            for (int j = 0; j < 4; ++j) *(short8_t*)(bw + 8 * j) = z;
        }
        __syncthreads();
    }

    const int B6 = NB * NR;
    #pragma unroll
    for (int n = 0; n < 2; ++n) {
        f32x4 v = n ? acc1 : acc0;
        int col = nh * 32 + n * 16 + lr;
        if (col < NOUT) {
            #pragma unroll
            for (int j = 0; j < 4; ++j) {
                int row = mt * 16 + lq * 4 + j;
                if (row < nvalid) {
                    int smp = sRow[row];
                    if (col < NR) out[smp * NR + col] = v[j] + breg[g * NR + col];
                    else          out[B6 + smp * NKC + (col - NR)] = v[j] + bcls[g * NKC + (col - NR)];
                }
            }
        }
    }
}

// ---- tier-4: exact fp32, one wave per sample ----
__global__ void fallback_kernel(const float* __restrict__ feats, const int* __restrict__ roi,
                                const float* __restrict__ Wreg, const float* __restrict__ breg,
                                const float* __restrict__ Wcls, const float* __restrict__ bcls,
                                float* __restrict__ out) {
    int i = blockIdx.x;
    int lane = threadIdx.x;
    int g = roi[i];
    const float* frow = feats + (size_t)i * ND;
    float f[32];
    #pragma unroll
    for (int q = 0; q < 32; ++q) f[q] = frow[lane + 64 * q];
    for (int o = 0; o < NOUT; ++o) {
        const float* wrow = (o < NR) ? Wreg + ((size_t)g * NR + o) * ND
                                     : Wcls + ((size_t)g * NKC + (o - NR)) * ND;
        float p = 0.f;
        #pragma unroll
        for (int q = 0; q < 32; ++q) p += f[q] * wrow[lane + 64 * q];
        #pragma unroll
        for (int s = 32; s; s >>= 1) p += __shfl_xor(p, s);
        if (lane == 0) {
            if (o < NR) out[i * NR + o] = p + breg[g * NR + o];
            else        out[NB * NR + i * NKC + (o - NR)] = p + bcls[g * NKC + (o - NR)];
        }
    }
}

extern "C" void kernel_launch(void* const* d_in, const int* in_sizes, int n_in,
                              void* d_out, int out_size, void* d_ws, size_t ws_size,
                              hipStream_t stream) {
    const float* feats = (const float*)d_in[0];
    const int*   roi   = (const int*)d_in[1];
    const float* Wreg  = (const float*)d_in[2];
    const float* breg  = (const float*)d_in[3];
    const float* Wcls  = (const float*)d_in[4];
    const float* bcls  = (const float*)d_in[5];
    float* out = (float*)d_out;

    const size_t wbfBytes = (size_t)NG * 131072 * 2;              // 2 MB blob
    const size_t need_t1 = wbfBytes + 256 + (size_t)NG * NB * 4;  // blob + fixed-stride perm
    const size_t need_t3 = 256 + (size_t)NB * 4;                  // packed-perm path

    if (ws_size >= need_t1) {
        short* Wbf = (short*)d_ws;
        int* cnt   = (int*)((char*)d_ws + wbfBytes);
        int* perm  = cnt + 64;
        hipMemsetAsync(cnt, 0, 64, stream);
        prep_kernel<<<576, 256, 0, stream>>>(roi, cnt, perm, Wreg, Wcls, Wbf);
        gemm_res_kernel<<<NT16, 256, 0, stream>>>(feats, Wbf, breg, bcls, cnt, perm, out);
    } else if (ws_size >= need_t3) {
        int* counts = (int*)d_ws;
        int* ranks  = counts + 8;
        int* perm   = counts + 64;
        hipMemsetAsync(counts, 0, 16 * sizeof(int), stream);
        hist_kernel<<<NB / 256, 256, 0, stream>>>(roi, counts);
        scatter_kernel<<<NB / 256, 256, 0, stream>>>(roi, counts, ranks, perm);
        gemm_kernel<<<MAXT, 256, 0, stream>>>(feats, Wreg, breg, Wcls, bcls, counts, perm, out, 0);
    } else {
        fallback_kernel<<<NB, 64, 0, stream>>>(feats, roi, Wreg, breg, Wcls, bcls, out);
    }
}

// Round 17
// 84.532 us; speedup vs baseline: 1.4103x; 1.4103x over previous
//
#include <hip/hip_runtime.h>
#include <hip/hip_bf16.h>

#define NB   16384
#define NG   8
#define ND   2048
#define NR   6
#define NKC  48
#define NOUT 54
#define NT32 (NB / 32 + NG)       // 520 tiles of 32 samples
#define LROW 136                  // tier-3 fallback gemm
#define BM   32
#define KC   128
#define NCH  (ND / KC)
#define MAXT (NB / BM + NG)

typedef __attribute__((ext_vector_type(8))) short short8_t;
typedef __attribute__((ext_vector_type(4))) float f32x4;

__device__ __forceinline__ unsigned short f2bf(float x) {
    union { float f; unsigned u; } v; v.f = x;
    unsigned r = v.u + 0x7FFFu + ((v.u >> 16) & 1u);   // RNE
    return (unsigned short)(r >> 16);
}

__device__ __forceinline__ short8_t cvt8(float4 a, float4 b) {
    short8_t s;
    s[0] = (short)f2bf(a.x); s[1] = (short)f2bf(a.y);
    s[2] = (short)f2bf(a.z); s[3] = (short)f2bf(a.w);
    s[4] = (short)f2bf(b.x); s[5] = (short)f2bf(b.y);
    s[6] = (short)f2bf(b.z); s[7] = (short)f2bf(b.w);
    return s;
}

__device__ __forceinline__ void gl_lds16(const void* g, void* s) {
    __builtin_amdgcn_global_load_lds(
        (const __attribute__((address_space(1))) void*)g,
        (__attribute__((address_space(3))) void*)s,
        16, 0, 0);
}

#define WAITV(N) do { asm volatile("s_waitcnt vmcnt(" #N ")" ::: "memory"); \
                      __builtin_amdgcn_sched_barrier(0); } while (0)
#define BAR() do { __builtin_amdgcn_s_barrier(); \
                   __builtin_amdgcn_sched_barrier(0); } while (0)

// ---- histogram (tier-3) ----
__global__ void hist_kernel(const int* __restrict__ roi, int* __restrict__ counts) {
    int i = blockIdx.x * 256 + threadIdx.x;
    int g = roi[i];
    int lane = threadIdx.x & 63;
    #pragma unroll
    for (int gg = 0; gg < NG; ++gg) {
        unsigned long long m = __ballot(g == gg);
        if (m && lane == (int)(__ffsll((unsigned long long)m) - 1))
            atomicAdd(&counts[gg], (int)__popcll(m));
    }
}

// ---- scatter into packed regions (tier-3) ----
__global__ void scatter_kernel(const int* __restrict__ roi, const int* __restrict__ counts,
                               int* __restrict__ ranks, int* __restrict__ perm) {
    int off[NG];
    int acc = 0;
    #pragma unroll
    for (int gg = 0; gg < NG; ++gg) { off[gg] = acc; acc += counts[gg]; }
    int i = blockIdx.x * 256 + threadIdx.x;
    int g = roi[i];
    int lane = threadIdx.x & 63;
    #pragma unroll
    for (int gg = 0; gg < NG; ++gg) {
        unsigned long long m = __ballot(g == gg);
        if (!m) continue;
        int leader = (int)(__ffsll((unsigned long long)m) - 1);
        int base = 0;
        if (lane == leader) base = atomicAdd(&ranks[gg], (int)__popcll(m));
        base = __shfl(base, leader);
        if (g == gg) {
            int rank = (int)__popcll(m & ((1ull << lane) - 1ull));
            perm[off[gg] + base + rank] = i;
        }
    }
}

// ---- prep: blocks 0..63 rank samples within group; 64..575 build W blob ----
// blob unit u (16B): l=u&63, q=(u>>6)&7, c=(u>>9)&31, g=u>>14; n=q>>1, ks=q&1
// content = W[g][n*16 + (l&15)][c*64 + ks*32 + (l>>4)*8 .. +8)
__global__ void prep_kernel(const int* __restrict__ roi, int* __restrict__ cnt,
                            int* __restrict__ rank,
                            const float* __restrict__ Wreg, const float* __restrict__ Wcls,
                            short* __restrict__ Wbf) {
    if (blockIdx.x < 64) {
        int i = blockIdx.x * 256 + threadIdx.x;
        int g = roi[i];
        int lane = threadIdx.x & 63;
        #pragma unroll
        for (int gg = 0; gg < NG; ++gg) {
            unsigned long long m = __ballot(g == gg);
            if (!m) continue;
            int leader = (int)(__ffsll((unsigned long long)m) - 1);
            int base = 0;
            if (lane == leader) base = atomicAdd(&cnt[gg], (int)__popcll(m));
            base = __shfl(base, leader);
            if (g == gg) {
                int r = (int)__popcll(m & ((1ull << lane) - 1ull));
                rank[i] = base + r;
            }
        }
    } else {
        int u = (blockIdx.x - 64) * 256 + threadIdx.x;   // 131072 units
        int l = u & 63;
        int q = (u >> 6) & 7;
        int c = (u >> 9) & 31;
        int g = u >> 14;
        int n = q >> 1, ks = q & 1;
        int row = n * 16 + (l & 15);
        int k   = c * 64 + ks * 32 + (l >> 4) * 8;
        short8_t v = {0, 0, 0, 0, 0, 0, 0, 0};
        if (row < NOUT) {
            const float* s = (row < NR) ? Wreg + (size_t)(g * NR + row) * ND + k
                                        : Wcls + (size_t)(g * NKC + row - NR) * ND + k;
            float4 a = *(const float4*)s;
            float4 b = *(const float4*)(s + 4);
            v = cvt8(a, b);
        }
        *(short8_t*)(Wbf + (size_t)u * 8) = v;
    }
}

// ---- castgather: index-ordered streaming read of feats (DRAM-optimal),
//      fp32->bf16, write row to packed sorted position (4KB contiguous) ----
__global__ void castgather_kernel(const float* __restrict__ feats,
                                  const int* __restrict__ roi,
                                  const int* __restrict__ cnt, const int* __restrict__ rank,
                                  short* __restrict__ gathered, int* __restrict__ permp) {
    int b = blockIdx.x;               // one block per sample, address order
    int tid = threadIdx.x;            // 256 threads x 8 floats = 2048
    int g = roi[b];
    int pre = 0;
    #pragma unroll
    for (int gg = 0; gg < NG; ++gg) if (gg < g) pre += cnt[gg];
    int pos = pre + rank[b];
    if (tid == 0) permp[pos] = b;
    const float* src = feats + (size_t)b * ND + tid * 8;
    float4 a0 = *(const float4*)(src);
    float4 a1 = *(const float4*)(src + 4);
    *(short8_t*)(gathered + (size_t)pos * ND + tid * 8) = cvt8(a0, a1);
}

// ---- primary GEMM on sorted bf16 A (R13 skeleton, proven wait counts) ----
// 520 blocks x 4 waves, 4 blocks/CU. Tile = 32 samples (packed positions
// [t32, t32+32)) x 64 cols. Chunk KC=64: A 4KB (1 gl_lds/wave, XOR-piece
// swizzle via per-lane source) + B 8KB (2 gl_lds/wave from blob). Ring-3,
// WAITV(6)/3/0, raw barriers. Wave w: rows (w>>1)*16, cols (w&1)*32.
__launch_bounds__(256, 4)
__global__ void gemm_s_kernel(const short* __restrict__ gathered,
                              const short* __restrict__ Wbf,
                              const float* __restrict__ breg, const float* __restrict__ bcls,
                              const int* __restrict__ cnt, const int* __restrict__ permp,
                              float* __restrict__ out) {
    __shared__ __align__(16) char lds[3][12288];   // slot: A 4KB @0 | B 8KB @4096

    int tid = threadIdx.x, w = tid >> 6, l = tid & 63, lr = l & 15, lq = l >> 4;
    int mt = w >> 1, nh = w & 1;

    int ts[NG + 1]; ts[0] = 0;
    int pre[NG]; int acc_ = 0;
    #pragma unroll
    for (int gg = 0; gg < NG; ++gg) {
        pre[gg] = acc_;
        acc_ += cnt[gg];
        ts[gg + 1] = ts[gg] + ((cnt[gg] + 31) >> 5);
    }
    int b = blockIdx.x;
    if (b >= ts[NG]) return;
    int g = 0;
    #pragma unroll
    for (int gg = 0; gg < NG; ++gg) if (b >= ts[gg + 1]) g = gg + 1;
    int rbase = (b - ts[g]) * 32;
    int nv = cnt[g] - rbase; if (nv > 32) nv = 32;
    int t32 = pre[g] + rbase;        // packed base position of this tile

    // A staging: lane l stages row rr = w*8 + (l>>3), piece (l&7)^(rr&7)
    int rr = w * 8 + (l >> 3);
    const char* aSrc = (const char*)gathered + ((size_t)t32 + rr) * 4096
                     + (((l & 7) ^ (rr & 7)) << 4);
    // B staging: wave w stages granules 2w, 2w+1 (1KB each, contiguous)
    const char* bSrc = (const char*)Wbf + (size_t)g * 262144 + 2 * w * 1024 + l * 16;

    // A read offsets (involution): row mt*16+lr, piece (ks*4+lq)^(lr&7)
    const int ra0 = (mt * 16 + lr) * 128 + ((((0 * 4) + lq) ^ (lr & 7)) << 4);
    const int ra1 = (mt * 16 + lr) * 128 + ((((1 * 4) + lq) ^ (lr & 7)) << 4);
    // B read offsets: granule (n*2+ks)*1024 + l*16, n = nh*2+cn
    const int rb00 = 4096 + ((nh * 2 + 0) * 2 + 0) * 1024 + l * 16;
    const int rb01 = 4096 + ((nh * 2 + 0) * 2 + 1) * 1024 + l * 16;
    const int rb10 = 4096 + ((nh * 2 + 1) * 2 + 0) * 1024 + l * 16;
    const int rb11 = 4096 + ((nh * 2 + 1) * 2 + 1) * 1024 + l * 16;

#define STAGE(cc, sl) do {                                                     \
        gl_lds16(aSrc + (size_t)(cc) * 128, &lds[sl][w * 1024 + l * 16]);      \
        const char* b_ = bSrc + (size_t)(cc) * 8192;                           \
        gl_lds16(b_,        &lds[sl][4096 + 2 * w * 1024 + l * 16]);           \
        gl_lds16(b_ + 1024, &lds[sl][4096 + 2 * w * 1024 + 1024 + l * 16]);    \
    } while (0)

    f32x4 acc0 = {0, 0, 0, 0}, acc1 = {0, 0, 0, 0};

    STAGE(0, 0); STAGE(1, 1);          // 6 outstanding per wave
    int csl = 0;
    #pragma unroll
    for (int c = 0; c < 32; ++c) {
        if (c + 2 < 32) STAGE(c + 2, (c + 2) % 3);   // 9 outstanding
        if (c < 30)       WAITV(6);                  // chunk c landed; 2 in flight
        else if (c == 30) WAITV(3);
        else              WAITV(0);
        BAR();
        {
            const char* s = &lds[csl][0];
            short8_t af0 = *(const short8_t*)(s + ra0);
            short8_t b00 = *(const short8_t*)(s + rb00);
            short8_t b10 = *(const short8_t*)(s + rb10);
            acc0 = __builtin_amdgcn_mfma_f32_16x16x32_bf16(af0, b00, acc0, 0, 0, 0);
            acc1 = __builtin_amdgcn_mfma_f32_16x16x32_bf16(af0, b10, acc1, 0, 0, 0);
            short8_t af1 = *(const short8_t*)(s + ra1);
            short8_t b01 = *(const short8_t*)(s + rb01);
            short8_t b11 = *(const short8_t*)(s + rb11);
            acc0 = __builtin_amdgcn_mfma_f32_16x16x32_bf16(af1, b01, acc0, 0, 0, 0);
            acc1 = __builtin_amdgcn_mfma_f32_16x16x32_bf16(af1, b11, acc1, 0, 0, 0);
        }
        BAR();
        csl = (csl == 2) ? 0 : csl + 1;
    }
#undef STAGE

    // epilogue: bias + scatter to routed rows
    const int B6 = NB * NR;
    #pragma unroll
    for (int cn = 0; cn < 2; ++cn) {
        f32x4 v = cn ? acc1 : acc0;
        int col = nh * 32 + cn * 16 + lr;
        if (col < NOUT) {
            float bias = (col < NR) ? breg[g * NR + col] : bcls[g * NKC + (col - NR)];
            #pragma unroll
            for (int j = 0; j < 4; ++j) {
                int row = mt * 16 + lq * 4 + j;
                if (row < nv) {
                    int smp = permp[t32 + row];
                    if (col < NR) out[smp * NR + col] = v[j] + bias;
                    else          out[B6 + smp * NKC + (col - NR)] = v[j] + bias;
                }
            }
        }
    }
}

// ---- tier-3 GEMM (proven R3 path, no ws blob needed) ----
__launch_bounds__(256, 3)
__global__ void gemm_kernel(const float* __restrict__ feats,
                            const float* __restrict__ Wreg, const float* __restrict__ breg,
                            const float* __restrict__ Wcls, const float* __restrict__ bcls,
                            const int* __restrict__ counts, const int* __restrict__ perm,
                            float* __restrict__ out, int stride) {
    __shared__ __align__(16) short Bsh[2][64][LROW];
    __shared__ int sRow[BM];

    int ts[NG + 1]; ts[0] = 0;
    int off[NG]; int acc = 0;
    #pragma unroll
    for (int gg = 0; gg < NG; ++gg) {
        int c = counts[gg];
        off[gg] = stride ? gg * stride : acc;
        acc += c;
        ts[gg + 1] = ts[gg] + (c + BM - 1) / BM;
    }
    int b = blockIdx.x;
    if (b >= ts[NG]) return;
    int g = 0;
    #pragma unroll
    for (int gg = 0; gg < NG; ++gg) if (b >= ts[gg + 1]) g = gg + 1;
    int gcnt  = counts[g];
    int goff  = off[g];
    int rbase = (b - ts[g]) * BM;
    int nvalid = gcnt - rbase; if (nvalid > BM) nvalid = BM;

    int tid = threadIdx.x;
    if (tid < BM) {
        int r = rbase + tid;
        if (r >= gcnt) r = gcnt - 1;
        sRow[tid] = perm[goff + r];
    }
    __syncthreads();

    int rB = tid >> 2;
    int cq = tid & 3;
    const float* wsrc = nullptr;
    if (rB < NR)        wsrc = Wreg + ((size_t)g * NR + rB) * ND + cq * 32;
    else if (rB < NOUT) wsrc = Wcls + ((size_t)g * NKC + (rB - NR)) * ND + cq * 32;

    int w = tid >> 6, l = tid & 63, lr = l & 15, lq = l >> 4;
    int mt = w & 1, nh = w >> 1;
    const float* aptr = feats + (size_t)sRow[mt * 16 + lr] * ND + lq * 8;
    const short* brp = (const short*)&Bsh[0][0][0] + (nh * 32 + lr) * LROW + lq * 8;

    f32x4 acc0 = {0, 0, 0, 0}, acc1 = {0, 0, 0, 0};
    float4 rb[8];

    if (wsrc) {
        #pragma unroll
        for (int i = 0; i < 8; ++i) rb[i] = *(const float4*)(wsrc + 4 * i);
    } else {
        #pragma unroll
        for (int i = 0; i < 8; ++i) rb[i] = make_float4(0.f, 0.f, 0.f, 0.f);
    }
    {
        short* bw = &Bsh[0][rB][cq * 32];
        #pragma unroll
        for (int j = 0; j < 4; ++j) *(short8_t*)(bw + 8 * j) = cvt8(rb[2 * j], rb[2 * j + 1]);
    }
    __syncthreads();

    #pragma unroll
    for (int c = 0; c < NCH; ++c) {
        const int cur = c & 1, nxt = cur ^ 1;
        if (c + 1 < NCH && wsrc) {
            const float* s = wsrc + (c + 1) * KC;
            #pragma unroll
            for (int i = 0; i < 8; ++i) rb[i] = *(const float4*)(s + 4 * i);
        }
        const short* bp = brp + cur * (64 * LROW);
        const float* ap = aptr + c * KC;
        #pragma unroll
        for (int ks = 0; ks < 4; ++ks) {
            float4 a0 = *(const float4*)(ap + ks * 32);
            float4 a1 = *(const float4*)(ap + ks * 32 + 4);
            short8_t af = cvt8(a0, a1);
            short8_t b0 = *(const short8_t*)(bp + ks * 32);
            short8_t b1 = *(const short8_t*)(bp + 16 * LROW + ks * 32);
            acc0 = __builtin_amdgcn_mfma_f32_16x16x32_bf16(af, b0, acc0, 0, 0, 0);
            acc1 = __builtin_amdgcn_mfma_f32_16x16x32_bf16(af, b1, acc1, 0, 0, 0);
        }
        if (c + 1 < NCH && wsrc) {
            short* bw = &Bsh[nxt][rB][cq * 32];
            #pragma unroll
            for (int j = 0; j < 4; ++j) *(short8_t*)(bw + 8 * j) = cvt8(rb[2 * j], rb[2 * j + 1]);
        } else if (c + 1 < NCH) {
            short8_t z = {0,0,0,0,0,0,0,0};
            short* bw = &Bsh[nxt][rB][cq * 32];
            #pragma unroll
            for (int j = 0; j < 4; ++j) *(short8_t*)(bw + 8 * j) = z;
        }
        __syncthreads();
    }

    const int B6 = NB * NR;
    #pragma unroll
    for (int n = 0; n < 2; ++n) {
        f32x4 v = n ? acc1 : acc0;
        int col = nh * 32 + n * 16 + lr;
        if (col < NOUT) {
            #pragma unroll
            for (int j = 0; j < 4; ++j) {
                int row = mt * 16 + lq * 4 + j;
                if (row < nvalid) {
                    int smp = sRow[row];
                    if (col < NR) out[smp * NR + col] = v[j] + breg[g * NR + col];
                    else          out[B6 + smp * NKC + (col - NR)] = v[j] + bcls[g * NKC + (col - NR)];
                }
            }
        }
    }
}

// ---- tier-4: exact fp32, one wave per sample ----
__global__ void fallback_kernel(const float* __restrict__ feats, const int* __restrict__ roi,
                                const float* __restrict__ Wreg, const float* __restrict__ breg,
                                const float* __restrict__ Wcls, const float* __restrict__ bcls,
                                float* __restrict__ out) {
    int i = blockIdx.x;
    int lane = threadIdx.x;
    int g = roi[i];
    const float* frow = feats + (size_t)i * ND;
    float f[32];
    #pragma unroll
    for (int q = 0; q < 32; ++q) f[q] = frow[lane + 64 * q];
    for (int o = 0; o < NOUT; ++o) {
        const float* wrow = (o < NR) ? Wreg + ((size_t)g * NR + o) * ND
                                     : Wcls + ((size_t)g * NKC + (o - NR)) * ND;
        float p = 0.f;
        #pragma unroll
        for (int q = 0; q < 32; ++q) p += f[q] * wrow[lane + 64 * q];
        #pragma unroll
        for (int s = 32; s; s >>= 1) p += __shfl_xor(p, s);
        if (lane == 0) {
            if (o < NR) out[i * NR + o] = p + breg[g * NR + o];
            else        out[NB * NR + i * NKC + (o - NR)] = p + bcls[g * NKC + (o - NR)];
        }
    }
}

extern "C" void kernel_launch(void* const* d_in, const int* in_sizes, int n_in,
                              void* d_out, int out_size, void* d_ws, size_t ws_size,
                              hipStream_t stream) {
    const float* feats = (const float*)d_in[0];
    const int*   roi   = (const int*)d_in[1];
    const float* Wreg  = (const float*)d_in[2];
    const float* breg  = (const float*)d_in[3];
    const float* Wcls  = (const float*)d_in[4];
    const float* bcls  = (const float*)d_in[5];
    float* out = (float*)d_out;

    const size_t wbfBytes = (size_t)NG * 131072 * 2;   // 2 MB blob @ 0
    const size_t cntOff   = 2u * 1024 * 1024;          // 64 ints
    const size_t rankOff  = cntOff + 256;              // NB ints
    const size_t permOff  = rankOff + (size_t)NB * 4;  // NB ints
    const size_t gathOff  = 4u * 1024 * 1024;          // (NB+32) x 4KB bf16 rows
    const size_t need_t1  = gathOff + (size_t)(NB + 32) * 4096;
    const size_t need_t3  = 256 + (size_t)NB * 4;

    if (ws_size >= need_t1) {
        short* Wbf     = (short*)d_ws;
        int*   cnt     = (int*)((char*)d_ws + cntOff);
        int*   rank    = (int*)((char*)d_ws + rankOff);
        int*   permp   = (int*)((char*)d_ws + permOff);
        short* gathered= (short*)((char*)d_ws + gathOff);
        hipMemsetAsync(cnt, 0, 64, stream);
        prep_kernel<<<576, 256, 0, stream>>>(roi, cnt, rank, Wreg, Wcls, Wbf);
        castgather_kernel<<<NB, 256, 0, stream>>>(feats, roi, cnt, rank, gathered, permp);
        gemm_s_kernel<<<NT32, 256, 0, stream>>>(gathered, Wbf, breg, bcls, cnt, permp, out);
    } else if (ws_size >= need_t3) {
        int* counts = (int*)d_ws;
        int* ranks  = counts + 8;
        int* perm   = counts + 64;
        hipMemsetAsync(counts, 0, 16 * sizeof(int), stream);
        hist_kernel<<<NB / 256, 256, 0, stream>>>(roi, counts);
        scatter_kernel<<<NB / 256, 256, 0, stream>>>(roi, counts, ranks, perm);
        gemm_kernel<<<MAXT, 256, 0, stream>>>(feats, Wreg, breg, Wcls, bcls, counts, perm, out, 0);
    } else {
        fallback_kernel<<<NB, 64, 0, stream>>>(feats, roi, Wreg, breg, Wcls, bcls, out);
    }
}